// Round 4
// baseline (382.935 us; speedup 1.0000x reference)
//
#include <hip/hip_runtime.h>
#include <hip/hip_bf16.h>
#include <stdint.h>

#define B_ 4
#define S_ 8192
#define HID 768
#define NTOK (B_ * S_)  // 32768

typedef unsigned short u16;
typedef __bf16 bf16x8 __attribute__((ext_vector_type(8)));
typedef float f32x4 __attribute__((ext_vector_type(4)));

// ---------------- hash parameters (host-computed, passed by value) ----------
struct HashP {
  unsigned long long mult[8][3];
  unsigned long long off[8];
};

static HashP make_hashp() {
  HashP hp;
  const long long max_int = 2147483647LL;  // 2^31 - 1
  int gi = 0;
  const int ngrams[2] = {2, 3};
  for (int t = 0; t < 2; ++t) {
    int n = ngrams[t];
    for (int h = 0; h < 4; ++h) {
      long long base = 17 + 10007 * 1 + 1543 * (n + 1) + 8191 * (h + 1);
      for (int p = 0; p < 3; ++p) hp.mult[gi][p] = 0ull;
      for (int p = 0; p < n; ++p) {
        long long v = (base + 32771LL * (p + 1) + 65537LL * (h + 1) * (p + 1)) % max_int;
        hp.mult[gi][p] = (unsigned long long)(v * 2 + 1);
      }
      hp.off[gi] = (unsigned long long)(((base * max_int) + 97LL * (n + h + 1)) % max_int);
      ++gi;
    }
  }
  return hp;
}

// ---------------- small helpers -------------------------------------------
__device__ __forceinline__ float b2f(u16 u) {
  union { unsigned int i; float f; } c;
  c.i = ((unsigned int)u) << 16;
  return c.f;
}
__device__ __forceinline__ u16 f2b(float f) {  // RNE
  union { float f; unsigned int i; } c;
  c.f = f;
  unsigned int r = c.i + 0x7fffu + ((c.i >> 16) & 1u);
  return (u16)(r >> 16);
}

// store 8 floats as 8 bf16 (16B)
__device__ __forceinline__ void store8b(u16* p, const float* f) {
  uint4 u;
  u.x = (unsigned)f2b(f[0]) | ((unsigned)f2b(f[1]) << 16);
  u.y = (unsigned)f2b(f[2]) | ((unsigned)f2b(f[3]) << 16);
  u.z = (unsigned)f2b(f[4]) | ((unsigned)f2b(f[5]) << 16);
  u.w = (unsigned)f2b(f[6]) | ((unsigned)f2b(f[7]) << 16);
  *reinterpret_cast<uint4*>(p) = u;
}
// load 8 bf16 -> 8 floats
struct F8 { float f[8]; };
__device__ __forceinline__ F8 load8b(const u16* p) {  // 16B-aligned
  uint4 u = *reinterpret_cast<const uint4*>(p);
  F8 r;
  r.f[0] = b2f((u16)(u.x & 0xffffu)); r.f[1] = b2f((u16)(u.x >> 16));
  r.f[2] = b2f((u16)(u.y & 0xffffu)); r.f[3] = b2f((u16)(u.y >> 16));
  r.f[4] = b2f((u16)(u.z & 0xffffu)); r.f[5] = b2f((u16)(u.z >> 16));
  r.f[6] = b2f((u16)(u.w & 0xffffu)); r.f[7] = b2f((u16)(u.w >> 16));
  return r;
}

// global -> LDS direct copy, 16 B per lane (CK addrspace-cast idiom)
__device__ __forceinline__ void gl_lds16(const void* g, void* l) {
  auto gp = reinterpret_cast<const __attribute__((address_space(1))) void*>(
      reinterpret_cast<uintptr_t>(g));
  auto lp = reinterpret_cast<__attribute__((address_space(3))) void*>(
      reinterpret_cast<uintptr_t>(l));
  __builtin_amdgcn_global_load_lds(gp, lp, 16, 0, 0);
}

// ---------------- kernel 0: convert Wk,Wv fp32 -> bf16 ---------------------
__global__ __launch_bounds__(256) void k_w2b(
    const float* __restrict__ wk, const float* __restrict__ wv,
    u16* __restrict__ wkb, u16* __restrict__ wvb) {
  int t = blockIdx.x * 256 + threadIdx.x;     // 0..147455, 8 elems each
  const float* src;
  u16* dst;
  int off;
  if (t < 73728) { src = wk; dst = wkb; off = t * 8; }
  else           { src = wv; dst = wvb; off = (t - 73728) * 8; }
  float4 a = *reinterpret_cast<const float4*>(src + off);
  float4 b = *reinterpret_cast<const float4*>(src + off + 4);
  float f[8] = {a.x, a.y, a.z, a.w, b.x, b.y, b.z, b.w};
  store8b(dst + off, f);
}

// ---------------- kernel 1: hash + embedding gather -> memory (bf16) -------
// memory[token][768] bf16; thread handles 8 consecutive channels of one head.
__global__ __launch_bounds__(256) void k_hash_gather(
    const int* __restrict__ ids, const float* __restrict__ emb,
    u16* __restrict__ mem, HashP hp) {
  int tid = blockIdx.x * 256 + threadIdx.x;
  int token = tid / 96;
  int j = tid - token * 96;  // 0..95 : head g = j/12, d0 = (j%12)*8
  if (token >= NTOK) return;
  int b = token >> 13;
  int s = token & (S_ - 1);
  int g = j / 12;
  int d0 = (j - g * 12) * 8;
  int n = (g < 4) ? 2 : 3;
  float f[8] = {0.f, 0.f, 0.f, 0.f, 0.f, 0.f, 0.f, 0.f};
  if (s >= n - 1) {
    const int* row = ids + b * S_;
    unsigned long long mix = 0ull;
    for (int p = 0; p < n; ++p)
      mix ^= (unsigned long long)(unsigned int)row[s - n + 1 + p] * hp.mult[g][p];
    unsigned long long id = (mix + hp.off[g]) % 1023ull + 1ull;
    const float* e = emb + ((size_t)g * 1024 + id) * 96 + d0;
    float4 a = *reinterpret_cast<const float4*>(e);
    float4 c = *reinterpret_cast<const float4*>(e + 4);
    f[0] = a.x; f[1] = a.y; f[2] = a.z; f[3] = a.w;
    f[4] = c.x; f[5] = c.y; f[6] = c.z; f[7] = c.w;
  }
  store8b(mem + (size_t)token * 768 + (size_t)j * 8, f);
}

// ---------------- kernel 2: kv = memory @ [Wk;Wv]^T  (MFMA GEMM) -----------
// A: [32768][768] bf16 (K-contig). W: [768][768] bf16 row-major = [N][K].
// Tile 128x128, BK=32, 4 waves, each wave 64x64 via 4x4 frags of 16x16x32.
__global__ __launch_bounds__(256) void k_gemm(
    const u16* __restrict__ A, const u16* __restrict__ Wk,
    const u16* __restrict__ Wv, u16* __restrict__ KV) {
  __shared__ u16 As[128 * 32];
  __shared__ u16 Bs[128 * 32];

  // XCD-aware swizzle: 12 N-tiles of one M-panel stay on one XCD.
  int L = blockIdx.x;          // 0..3071
  int xcd = L & 7;
  int idx = L >> 3;            // 0..383
  int mtl = idx / 12;          // 0..31
  int nt = idx - mtl * 12;     // 0..11
  int mt = xcd * 32 + mtl;     // 0..255
  const int m0 = mt * 128;
  const u16* Wbase = (nt < 6) ? (Wk + (size_t)nt * 128 * 768)
                              : (Wv + (size_t)(nt - 6) * 128 * 768);
  const int colbase = nt * 128;

  const int tid = threadIdx.x;
  const int lane = tid & 63;
  const int wv = tid >> 6;
  const int wr = (wv >> 1) * 64;  // wave row offset in tile
  const int wc = (wv & 1) * 64;   // wave col offset in tile
  const int m16 = lane & 15;
  const int g8 = (lane >> 4) * 8;

  f32x4 acc[4][4];
#pragma unroll
  for (int i = 0; i < 4; ++i)
#pragma unroll
    for (int j = 0; j < 4; ++j) acc[i][j] = (f32x4){0.f, 0.f, 0.f, 0.f};

  for (int kt = 0; kt < 24; ++kt) {
    const int k0 = kt * 32;
#pragma unroll
    for (int i = 0; i < 2; ++i) {
      int c = tid + i * 256;     // 16B chunk index, 0..511
      int row = c >> 2;
      int kk = (c & 3) * 8;
      gl_lds16(A + (size_t)(m0 + row) * 768 + k0 + kk, &As[c * 8]);
      gl_lds16(Wbase + (size_t)row * 768 + k0 + kk, &Bs[c * 8]);
    }
    __syncthreads();
    bf16x8 af[4], bfr[4];
#pragma unroll
    for (int mi = 0; mi < 4; ++mi)
      af[mi] = *reinterpret_cast<const bf16x8*>(&As[(wr + mi * 16 + m16) * 32 + g8]);
#pragma unroll
    for (int ni = 0; ni < 4; ++ni)
      bfr[ni] = *reinterpret_cast<const bf16x8*>(&Bs[(wc + ni * 16 + m16) * 32 + g8]);
#pragma unroll
    for (int mi = 0; mi < 4; ++mi)
#pragma unroll
      for (int ni = 0; ni < 4; ++ni)
        acc[mi][ni] = __builtin_amdgcn_mfma_f32_16x16x32_bf16(af[mi], bfr[ni],
                                                              acc[mi][ni], 0, 0, 0);
    __syncthreads();
  }

  // C/D layout: col = lane&15, row = (lane>>4)*4 + reg
  const int r0 = (lane >> 4) * 4;
#pragma unroll
  for (int mi = 0; mi < 4; ++mi) {
#pragma unroll
    for (int r = 0; r < 4; ++r) {
      int row = m0 + wr + mi * 16 + r0 + r;
      size_t base = (size_t)row * 1536 + colbase + wc;
#pragma unroll
      for (int ni = 0; ni < 4; ++ni)
        KV[base + ni * 16 + m16] = f2b(acc[mi][ni][r]);
    }
  }
}

// ---------------- kernel 3: RMSNorm(k), RMSNorm(v), gate, gated ------------
// wave per token; lane handles 12 consecutive channels.
__global__ __launch_bounds__(256) void k_epi(
    const u16* __restrict__ KV, const float* __restrict__ hid,
    const float* __restrict__ knw, const float* __restrict__ vnw,
    u16* __restrict__ gated) {
  int token = blockIdx.x * 4 + (threadIdx.x >> 6);
  int lane = threadIdx.x & 63;
  const int c0 = lane * 12;
  const u16* kr = KV + (size_t)token * 1536 + c0;
  const u16* vr = kr + 768;
  const float* hr = hid + (size_t)token * 768 + c0;

  float k[12], v[12], h[12];
#pragma unroll
  for (int q = 0; q < 3; ++q) {  // kv: ushort4 (8B); hid: float4 (16B)
    ushort4 a = *reinterpret_cast<const ushort4*>(kr + q * 4);
    ushort4 b = *reinterpret_cast<const ushort4*>(vr + q * 4);
    float4 c = *reinterpret_cast<const float4*>(hr + q * 4);
    k[q * 4 + 0] = b2f(a.x); k[q * 4 + 1] = b2f(a.y);
    k[q * 4 + 2] = b2f(a.z); k[q * 4 + 3] = b2f(a.w);
    v[q * 4 + 0] = b2f(b.x); v[q * 4 + 1] = b2f(b.y);
    v[q * 4 + 2] = b2f(b.z); v[q * 4 + 3] = b2f(b.w);
    h[q * 4 + 0] = c.x; h[q * 4 + 1] = c.y;
    h[q * 4 + 2] = c.z; h[q * 4 + 3] = c.w;
  }
  float ssk = 0.f, ssv = 0.f;
#pragma unroll
  for (int i = 0; i < 12; ++i) { ssk += k[i] * k[i]; ssv += v[i] * v[i]; }
#pragma unroll
  for (int off = 1; off < 64; off <<= 1) {
    ssk += __shfl_xor(ssk, off);
    ssv += __shfl_xor(ssv, off);
  }
  float rk = rsqrtf(ssk * (1.f / 768.f) + 1e-6f);
  float rv = rsqrtf(ssv * (1.f / 768.f) + 1e-6f);

  float dot = 0.f;
#pragma unroll
  for (int i = 0; i < 12; ++i) dot += h[i] * (k[i] * rk * knw[c0 + i]);
#pragma unroll
  for (int off = 1; off < 64; off <<= 1) dot += __shfl_xor(dot, off);
  float gate = 1.f / (1.f + expf(-dot * 0.03608439182435161f));  // 1/sqrt(768)

  float o[12];
#pragma unroll
  for (int i = 0; i < 12; ++i) o[i] = gate * v[i] * rv * vnw[c0 + i];

  u16* go = gated + (size_t)token * 768 + c0;
#pragma unroll
  for (int q = 0; q < 3; ++q) {
    ushort4 u;
    u.x = f2b(o[q * 4 + 0]); u.y = f2b(o[q * 4 + 1]);
    u.z = f2b(o[q * 4 + 2]); u.w = f2b(o[q * 4 + 3]);
    *reinterpret_cast<ushort4*>(go + q * 4) = u;
  }
}

// ---------------- kernel 4: causal depthwise conv (K=3), fp32 out ----------
__global__ __launch_bounds__(256) void k_conv(
    const u16* __restrict__ g, const float* __restrict__ cw,
    float* __restrict__ out) {
  int tid = blockIdx.x * 256 + threadIdx.x;
  int token = tid / 96;
  int j = tid - token * 96;
  if (token >= NTOK) return;
  int s = token & (S_ - 1);
  int c0 = j * 8;

  float w[8][3];
#pragma unroll
  for (int i = 0; i < 8; ++i)
#pragma unroll
    for (int kk = 0; kk < 3; ++kk) w[i][kk] = cw[(c0 + i) * 3 + kk];

  float acc[8] = {0.f, 0.f, 0.f, 0.f, 0.f, 0.f, 0.f, 0.f};
#pragma unroll
  for (int kk = 0; kk < 3; ++kk) {
    int d = kk - 2;
    if (s + d < 0) continue;
    F8 x = load8b(g + (size_t)(token + d) * 768 + c0);
#pragma unroll
    for (int i = 0; i < 8; ++i) acc[i] += x.f[i] * w[i][kk];
  }
  float* op = out + (size_t)token * 768 + c0;
  *reinterpret_cast<float4*>(op) = make_float4(acc[0], acc[1], acc[2], acc[3]);
  *reinterpret_cast<float4*>(op + 4) = make_float4(acc[4], acc[5], acc[6], acc[7]);
}

// ---------------- launch ---------------------------------------------------
extern "C" void kernel_launch(void* const* d_in, const int* in_sizes, int n_in,
                              void* d_out, int out_size, void* d_ws, size_t ws_size,
                              hipStream_t stream) {
  const float* hid = (const float*)d_in[0];
  const int* ids = (const int*)d_in[1];
  const float* emb = (const float*)d_in[2];
  const float* wk  = (const float*)d_in[3];
  const float* wvw = (const float*)d_in[4];
  const float* knw = (const float*)d_in[5];
  const float* vnw = (const float*)d_in[6];
  const float* cw  = (const float*)d_in[7];
  float* out = (float*)d_out;

  char* ws = (char*)d_ws;
  u16* mem = (u16*)ws;                        // 32768*768*2  = 50,331,648 B
  u16* kv  = (u16*)(ws + 50331648);           // 32768*1536*2 = 100,663,296 B
  u16* wkb = (u16*)(ws + 150994944);          // 768*768*2 = 1,179,648 B
  u16* wvb = (u16*)(ws + 152174592);          // 768*768*2
  u16* gated = mem;                           // reuse: memory dead after GEMM

  HashP hp = make_hashp();

  k_w2b<<<576, 256, 0, stream>>>(wk, wvw, wkb, wvb);
  k_hash_gather<<<12288, 256, 0, stream>>>(ids, emb, mem, hp);
  k_gemm<<<3072, 256, 0, stream>>>(mem, wkb, wvb, kv);
  k_epi<<<8192, 256, 0, stream>>>(kv, hid, knw, vnw, gated);
  k_conv<<<12288, 256, 0, stream>>>(gated, cw, out);
}

// Round 9
// 346.423 us; speedup vs baseline: 1.1054x; 1.1054x over previous
//
#include <hip/hip_runtime.h>
#include <hip/hip_bf16.h>
#include <stdint.h>

#define B_ 4
#define S_ 8192
#define HID 768
#define NTOK (B_ * S_)  // 32768

typedef unsigned short u16;
typedef __bf16 bf16x8 __attribute__((ext_vector_type(8)));
typedef float f32x4 __attribute__((ext_vector_type(4)));

// ---------------- hash parameters (host-computed, passed by value) ----------
struct HashP {
  unsigned long long mult[8][3];
  unsigned long long off[8];
};

static HashP make_hashp() {
  HashP hp;
  const long long max_int = 2147483647LL;  // 2^31 - 1
  int gi = 0;
  const int ngrams[2] = {2, 3};
  for (int t = 0; t < 2; ++t) {
    int n = ngrams[t];
    for (int h = 0; h < 4; ++h) {
      long long base = 17 + 10007 * 1 + 1543 * (n + 1) + 8191 * (h + 1);
      for (int p = 0; p < 3; ++p) hp.mult[gi][p] = 0ull;
      for (int p = 0; p < n; ++p) {
        long long v = (base + 32771LL * (p + 1) + 65537LL * (h + 1) * (p + 1)) % max_int;
        hp.mult[gi][p] = (unsigned long long)(v * 2 + 1);
      }
      hp.off[gi] = (unsigned long long)(((base * max_int) + 97LL * (n + h + 1)) % max_int);
      ++gi;
    }
  }
  return hp;
}

// ---------------- small helpers -------------------------------------------
__device__ __forceinline__ float b2f(u16 u) {
  union { unsigned int i; float f; } c;
  c.i = ((unsigned int)u) << 16;
  return c.f;
}
__device__ __forceinline__ u16 f2b(float f) {  // RNE
  union { float f; unsigned int i; } c;
  c.f = f;
  unsigned int r = c.i + 0x7fffu + ((c.i >> 16) & 1u);
  return (u16)(r >> 16);
}

// store 8 floats as 8 bf16 (16B)
__device__ __forceinline__ void store8b(u16* p, const float* f) {
  uint4 u;
  u.x = (unsigned)f2b(f[0]) | ((unsigned)f2b(f[1]) << 16);
  u.y = (unsigned)f2b(f[2]) | ((unsigned)f2b(f[3]) << 16);
  u.z = (unsigned)f2b(f[4]) | ((unsigned)f2b(f[5]) << 16);
  u.w = (unsigned)f2b(f[6]) | ((unsigned)f2b(f[7]) << 16);
  *reinterpret_cast<uint4*>(p) = u;
}
// load 8 bf16 -> 8 floats (works for global or LDS pointers)
struct F8 { float f[8]; };
__device__ __forceinline__ F8 load8b(const u16* p) {  // 16B-aligned
  uint4 u = *reinterpret_cast<const uint4*>(p);
  F8 r;
  r.f[0] = b2f((u16)(u.x & 0xffffu)); r.f[1] = b2f((u16)(u.x >> 16));
  r.f[2] = b2f((u16)(u.y & 0xffffu)); r.f[3] = b2f((u16)(u.y >> 16));
  r.f[4] = b2f((u16)(u.z & 0xffffu)); r.f[5] = b2f((u16)(u.z >> 16));
  r.f[6] = b2f((u16)(u.w & 0xffffu)); r.f[7] = b2f((u16)(u.w >> 16));
  return r;
}

// global -> LDS direct copy, 16 B per lane (CK addrspace-cast idiom)
__device__ __forceinline__ void gl_lds16(const void* g, void* l) {
  auto gp = reinterpret_cast<const __attribute__((address_space(1))) void*>(
      reinterpret_cast<uintptr_t>(g));
  auto lp = reinterpret_cast<__attribute__((address_space(3))) void*>(
      reinterpret_cast<uintptr_t>(l));
  __builtin_amdgcn_global_load_lds(gp, lp, 16, 0, 0);
}

// ---------------- kernel 0: convert Wk,Wv fp32 -> bf16 ---------------------
__global__ __launch_bounds__(256) void k_w2b(
    const float* __restrict__ wk, const float* __restrict__ wv,
    u16* __restrict__ wkb, u16* __restrict__ wvb) {
  int t = blockIdx.x * 256 + threadIdx.x;     // 0..147455, 8 elems each
  const float* src;
  u16* dst;
  int off;
  if (t < 73728) { src = wk; dst = wkb; off = t * 8; }
  else           { src = wv; dst = wvb; off = (t - 73728) * 8; }
  float4 a = *reinterpret_cast<const float4*>(src + off);
  float4 b = *reinterpret_cast<const float4*>(src + off + 4);
  float f[8] = {a.x, a.y, a.z, a.w, b.x, b.y, b.z, b.w};
  store8b(dst + off, f);
}

// ---------------- kernel 1: hash + embedding gather -> memory (bf16) -------
__global__ __launch_bounds__(256) void k_hash_gather(
    const int* __restrict__ ids, const float* __restrict__ emb,
    u16* __restrict__ mem, HashP hp) {
  int tid = blockIdx.x * 256 + threadIdx.x;
  int token = tid / 96;
  int j = tid - token * 96;  // 0..95 : head g = j/12, d0 = (j%12)*8
  if (token >= NTOK) return;
  int b = token >> 13;
  int s = token & (S_ - 1);
  int g = j / 12;
  int d0 = (j - g * 12) * 8;
  int n = (g < 4) ? 2 : 3;
  float f[8] = {0.f, 0.f, 0.f, 0.f, 0.f, 0.f, 0.f, 0.f};
  if (s >= n - 1) {
    const int* row = ids + b * S_;
    unsigned long long mix = 0ull;
    for (int p = 0; p < n; ++p)
      mix ^= (unsigned long long)(unsigned int)row[s - n + 1 + p] * hp.mult[g][p];
    unsigned long long id = (mix + hp.off[g]) % 1023ull + 1ull;
    const float* e = emb + ((size_t)g * 1024 + id) * 96 + d0;
    float4 a = *reinterpret_cast<const float4*>(e);
    float4 c = *reinterpret_cast<const float4*>(e + 4);
    f[0] = a.x; f[1] = a.y; f[2] = a.z; f[3] = a.w;
    f[4] = c.x; f[5] = c.y; f[6] = c.z; f[7] = c.w;
  }
  store8b(mem + (size_t)token * 768 + (size_t)j * 8, f);
}

// ---------------- kernel 2: kv = memory @ [Wk;Wv]^T  (MFMA GEMM) -----------
// UNCHANGED (control for counter attribution).
__global__ __launch_bounds__(256) void k_gemm(
    const u16* __restrict__ A, const u16* __restrict__ Wk,
    const u16* __restrict__ Wv, u16* __restrict__ KV) {
  __shared__ u16 As[128 * 32];
  __shared__ u16 Bs[128 * 32];

  int L = blockIdx.x;          // 0..3071
  int xcd = L & 7;
  int idx = L >> 3;            // 0..383
  int mtl = idx / 12;          // 0..31
  int nt = idx - mtl * 12;     // 0..11
  int mt = xcd * 32 + mtl;     // 0..255
  const int m0 = mt * 128;
  const u16* Wbase = (nt < 6) ? (Wk + (size_t)nt * 128 * 768)
                              : (Wv + (size_t)(nt - 6) * 128 * 768);
  const int colbase = nt * 128;

  const int tid = threadIdx.x;
  const int lane = tid & 63;
  const int wv = tid >> 6;
  const int wr = (wv >> 1) * 64;
  const int wc = (wv & 1) * 64;
  const int m16 = lane & 15;
  const int g8 = (lane >> 4) * 8;

  f32x4 acc[4][4];
#pragma unroll
  for (int i = 0; i < 4; ++i)
#pragma unroll
    for (int j = 0; j < 4; ++j) acc[i][j] = (f32x4){0.f, 0.f, 0.f, 0.f};

  for (int kt = 0; kt < 24; ++kt) {
    const int k0 = kt * 32;
#pragma unroll
    for (int i = 0; i < 2; ++i) {
      int c = tid + i * 256;
      int row = c >> 2;
      int kk = (c & 3) * 8;
      gl_lds16(A + (size_t)(m0 + row) * 768 + k0 + kk, &As[c * 8]);
      gl_lds16(Wbase + (size_t)row * 768 + k0 + kk, &Bs[c * 8]);
    }
    __syncthreads();
    bf16x8 af[4], bfr[4];
#pragma unroll
    for (int mi = 0; mi < 4; ++mi)
      af[mi] = *reinterpret_cast<const bf16x8*>(&As[(wr + mi * 16 + m16) * 32 + g8]);
#pragma unroll
    for (int ni = 0; ni < 4; ++ni)
      bfr[ni] = *reinterpret_cast<const bf16x8*>(&Bs[(wc + ni * 16 + m16) * 32 + g8]);
#pragma unroll
    for (int mi = 0; mi < 4; ++mi)
#pragma unroll
      for (int ni = 0; ni < 4; ++ni)
        acc[mi][ni] = __builtin_amdgcn_mfma_f32_16x16x32_bf16(af[mi], bfr[ni],
                                                              acc[mi][ni], 0, 0, 0);
    __syncthreads();
  }

  const int r0 = (lane >> 4) * 4;
#pragma unroll
  for (int mi = 0; mi < 4; ++mi) {
#pragma unroll
    for (int r = 0; r < 4; ++r) {
      int row = m0 + wr + mi * 16 + r0 + r;
      size_t base = (size_t)row * 1536 + colbase + wc;
#pragma unroll
      for (int ni = 0; ni < 4; ++ni)
        KV[base + ni * 16 + m16] = f2b(acc[mi][ni][r]);
    }
  }
}

// ---------------- kernel 3: fused RMSNorm+gate+conv ------------------------
// Block = 32 output tokens + 2-token recompute halo. Phase 1: wave-per-token
// epi -> gated rows in LDS (bf16, stride 776). Phase 2: causal K=3 conv.
// Phase-2 job count: 32 tokens x 96 chunks(8ch) = 3072 jobs = 256 thr x 12 it
// (round-7 bug was 384 jobs -> only channels 0..95 written).
#define T_TOK 32
#define LROW 776   // 768 + 8 pad (u16)
__global__ __launch_bounds__(256) void k_epiconv(
    const u16* __restrict__ KV, const float* __restrict__ hid,
    const float* __restrict__ knw, const float* __restrict__ vnw,
    const float* __restrict__ cw, float* __restrict__ out) {
  __shared__ u16 gl[(T_TOK + 2) * LROW];  // 52,768 B

  const int t0 = blockIdx.x * T_TOK;
  const int s0 = t0 & (S_ - 1);
  const int w = threadIdx.x >> 6;
  const int lane = threadIdx.x & 63;
  const int c0 = lane * 12;

  // ---- phase 1: epi for jobs j=0..33 (token t0+j-2), wave-strided ----
  for (int j = w; j < T_TOK + 2; j += 4) {
    if (!(s0 == 0 && j < 2)) {  // skip nonexistent tokens before sequence start
      const int token = t0 + j - 2;
      const u16* kr = KV + (size_t)token * 1536 + c0;
      const u16* vr = kr + 768;
      const float* hr = hid + (size_t)token * 768 + c0;

      float k[12], v[12], h[12];
#pragma unroll
      for (int q = 0; q < 3; ++q) {
        ushort4 a = *reinterpret_cast<const ushort4*>(kr + q * 4);
        ushort4 b = *reinterpret_cast<const ushort4*>(vr + q * 4);
        float4 c = *reinterpret_cast<const float4*>(hr + q * 4);
        k[q * 4 + 0] = b2f(a.x); k[q * 4 + 1] = b2f(a.y);
        k[q * 4 + 2] = b2f(a.z); k[q * 4 + 3] = b2f(a.w);
        v[q * 4 + 0] = b2f(b.x); v[q * 4 + 1] = b2f(b.y);
        v[q * 4 + 2] = b2f(b.z); v[q * 4 + 3] = b2f(b.w);
        h[q * 4 + 0] = c.x; h[q * 4 + 1] = c.y;
        h[q * 4 + 2] = c.z; h[q * 4 + 3] = c.w;
      }
      float ssk = 0.f, ssv = 0.f;
#pragma unroll
      for (int i = 0; i < 12; ++i) { ssk += k[i] * k[i]; ssv += v[i] * v[i]; }
#pragma unroll
      for (int off = 1; off < 64; off <<= 1) {
        ssk += __shfl_xor(ssk, off);
        ssv += __shfl_xor(ssv, off);
      }
      float rk = rsqrtf(ssk * (1.f / 768.f) + 1e-6f);
      float rv = rsqrtf(ssv * (1.f / 768.f) + 1e-6f);

      float dot = 0.f;
#pragma unroll
      for (int i = 0; i < 12; ++i) dot += h[i] * (k[i] * rk * knw[c0 + i]);
#pragma unroll
      for (int off = 1; off < 64; off <<= 1) dot += __shfl_xor(dot, off);
      float gate = 1.f / (1.f + expf(-dot * 0.03608439182435161f));  // 1/sqrt(768)

      u16* go = &gl[j * LROW + c0];
#pragma unroll
      for (int q = 0; q < 3; ++q) {
        ushort4 u;
        u.x = f2b(gate * v[q * 4 + 0] * rv * vnw[c0 + q * 4 + 0]);
        u.y = f2b(gate * v[q * 4 + 1] * rv * vnw[c0 + q * 4 + 1]);
        u.z = f2b(gate * v[q * 4 + 2] * rv * vnw[c0 + q * 4 + 2]);
        u.w = f2b(gate * v[q * 4 + 3] * rv * vnw[c0 + q * 4 + 3]);
        *reinterpret_cast<ushort4*>(go + q * 4) = u;
      }
    }
  }
  __syncthreads();

  // ---- phase 2: conv; 3072 jobs (32 tokens x 96 chunks of 8 ch) ----
#pragma unroll
  for (int it = 0; it < 12; ++it) {
    int job = threadIdx.x + it * 256;
    int r = job / 96;
    int cg = job - r * 96;
    int cc0 = cg * 8;
    int s = s0 + r;

    float acc[8] = {0.f, 0.f, 0.f, 0.f, 0.f, 0.f, 0.f, 0.f};
    if (s >= 2) {
      F8 x0 = load8b(&gl[r * LROW + cc0]);          // d=-2 (kk=0)
#pragma unroll
      for (int i = 0; i < 8; ++i) acc[i] += x0.f[i] * cw[(cc0 + i) * 3 + 0];
    }
    if (s >= 1) {
      F8 x1 = load8b(&gl[(r + 1) * LROW + cc0]);    // d=-1 (kk=1)
#pragma unroll
      for (int i = 0; i < 8; ++i) acc[i] += x1.f[i] * cw[(cc0 + i) * 3 + 1];
    }
    {
      F8 x2 = load8b(&gl[(r + 2) * LROW + cc0]);    // d=0  (kk=2)
#pragma unroll
      for (int i = 0; i < 8; ++i) acc[i] += x2.f[i] * cw[(cc0 + i) * 3 + 2];
    }
    float* op = out + (size_t)(t0 + r) * 768 + cc0;
    *reinterpret_cast<float4*>(op) = make_float4(acc[0], acc[1], acc[2], acc[3]);
    *reinterpret_cast<float4*>(op + 4) = make_float4(acc[4], acc[5], acc[6], acc[7]);
  }
}

// ---------------- launch ---------------------------------------------------
extern "C" void kernel_launch(void* const* d_in, const int* in_sizes, int n_in,
                              void* d_out, int out_size, void* d_ws, size_t ws_size,
                              hipStream_t stream) {
  const float* hid = (const float*)d_in[0];
  const int* ids = (const int*)d_in[1];
  const float* emb = (const float*)d_in[2];
  const float* wk  = (const float*)d_in[3];
  const float* wvw = (const float*)d_in[4];
  const float* knw = (const float*)d_in[5];
  const float* vnw = (const float*)d_in[6];
  const float* cw  = (const float*)d_in[7];
  float* out = (float*)d_out;

  char* ws = (char*)d_ws;
  u16* mem = (u16*)ws;                        // 32768*768*2  = 50,331,648 B
  u16* kv  = (u16*)(ws + 50331648);           // 32768*1536*2 = 100,663,296 B
  u16* wkb = (u16*)(ws + 150994944);          // 768*768*2 = 1,179,648 B
  u16* wvb = (u16*)(ws + 152174592);          // 768*768*2

  HashP hp = make_hashp();

  k_w2b<<<576, 256, 0, stream>>>(wk, wvw, wkb, wvb);
  k_hash_gather<<<12288, 256, 0, stream>>>(ids, emb, mem, hp);
  k_gemm<<<3072, 256, 0, stream>>>(mem, wkb, wvb, kv);
  k_epiconv<<<1024, 256, 0, stream>>>(kv, hid, knw, vnw, cw, out);
}

// Round 13
// 331.393 us; speedup vs baseline: 1.1555x; 1.0454x over previous
//
#include <hip/hip_runtime.h>
#include <hip/hip_bf16.h>
#include <stdint.h>

#define B_ 4
#define S_ 8192
#define HID 768
#define NTOK (B_ * S_)  // 32768

typedef unsigned short u16;
typedef __bf16 bf16x8 __attribute__((ext_vector_type(8)));
typedef float f32x4 __attribute__((ext_vector_type(4)));

// ---------------- hash parameters (host-computed, passed by value) ----------
struct HashP {
  unsigned long long mult[8][3];
  unsigned long long off[8];
};

static HashP make_hashp() {
  HashP hp;
  const long long max_int = 2147483647LL;  // 2^31 - 1
  int gi = 0;
  const int ngrams[2] = {2, 3};
  for (int t = 0; t < 2; ++t) {
    int n = ngrams[t];
    for (int h = 0; h < 4; ++h) {
      long long base = 17 + 10007 * 1 + 1543 * (n + 1) + 8191 * (h + 1);
      for (int p = 0; p < 3; ++p) hp.mult[gi][p] = 0ull;
      for (int p = 0; p < n; ++p) {
        long long v = (base + 32771LL * (p + 1) + 65537LL * (h + 1) * (p + 1)) % max_int;
        hp.mult[gi][p] = (unsigned long long)(v * 2 + 1);
      }
      hp.off[gi] = (unsigned long long)(((base * max_int) + 97LL * (n + h + 1)) % max_int);
      ++gi;
    }
  }
  return hp;
}

// ---------------- small helpers -------------------------------------------
__device__ __forceinline__ float b2f(u16 u) {
  union { unsigned int i; float f; } c;
  c.i = ((unsigned int)u) << 16;
  return c.f;
}
__device__ __forceinline__ u16 f2b(float f) {  // RNE
  union { float f; unsigned int i; } c;
  c.f = f;
  unsigned int r = c.i + 0x7fffu + ((c.i >> 16) & 1u);
  return (u16)(r >> 16);
}

// store 8 floats as 8 bf16 (16B)
__device__ __forceinline__ void store8b(u16* p, const float* f) {
  uint4 u;
  u.x = (unsigned)f2b(f[0]) | ((unsigned)f2b(f[1]) << 16);
  u.y = (unsigned)f2b(f[2]) | ((unsigned)f2b(f[3]) << 16);
  u.z = (unsigned)f2b(f[4]) | ((unsigned)f2b(f[5]) << 16);
  u.w = (unsigned)f2b(f[6]) | ((unsigned)f2b(f[7]) << 16);
  *reinterpret_cast<uint4*>(p) = u;
}
// load 8 bf16 -> 8 floats (works for global or LDS pointers)
struct F8 { float f[8]; };
__device__ __forceinline__ F8 load8b(const u16* p) {  // 16B-aligned
  uint4 u = *reinterpret_cast<const uint4*>(p);
  F8 r;
  r.f[0] = b2f((u16)(u.x & 0xffffu)); r.f[1] = b2f((u16)(u.x >> 16));
  r.f[2] = b2f((u16)(u.y & 0xffffu)); r.f[3] = b2f((u16)(u.y >> 16));
  r.f[4] = b2f((u16)(u.z & 0xffffu)); r.f[5] = b2f((u16)(u.z >> 16));
  r.f[6] = b2f((u16)(u.w & 0xffffu)); r.f[7] = b2f((u16)(u.w >> 16));
  return r;
}

// global -> LDS direct copy, 16 B per lane (CK addrspace-cast idiom)
__device__ __forceinline__ void gl_lds16(const void* g, void* l) {
  auto gp = reinterpret_cast<const __attribute__((address_space(1))) void*>(
      reinterpret_cast<uintptr_t>(g));
  auto lp = reinterpret_cast<__attribute__((address_space(3))) void*>(
      reinterpret_cast<uintptr_t>(l));
  __builtin_amdgcn_global_load_lds(gp, lp, 16, 0, 0);
}

// ---------------- kernel 0: convert Wk,Wv fp32 -> bf16 ---------------------
__global__ __launch_bounds__(256) void k_w2b(
    const float* __restrict__ wk, const float* __restrict__ wv,
    u16* __restrict__ wkb, u16* __restrict__ wvb) {
  int t = blockIdx.x * 256 + threadIdx.x;     // 0..147455, 8 elems each
  const float* src;
  u16* dst;
  int off;
  if (t < 73728) { src = wk; dst = wkb; off = t * 8; }
  else           { src = wv; dst = wvb; off = (t - 73728) * 8; }
  float4 a = *reinterpret_cast<const float4*>(src + off);
  float4 b = *reinterpret_cast<const float4*>(src + off + 4);
  float f[8] = {a.x, a.y, a.z, a.w, b.x, b.y, b.z, b.w};
  store8b(dst + off, f);
}

// ---------------- kernel 1: hash + embedding gather -> memory (bf16) -------
// UNCHANGED (control).
__global__ __launch_bounds__(256) void k_hash_gather(
    const int* __restrict__ ids, const float* __restrict__ emb,
    u16* __restrict__ mem, HashP hp) {
  int tid = blockIdx.x * 256 + threadIdx.x;
  int token = tid / 96;
  int j = tid - token * 96;  // 0..95 : head g = j/12, d0 = (j%12)*8
  if (token >= NTOK) return;
  int b = token >> 13;
  int s = token & (S_ - 1);
  int g = j / 12;
  int d0 = (j - g * 12) * 8;
  int n = (g < 4) ? 2 : 3;
  float f[8] = {0.f, 0.f, 0.f, 0.f, 0.f, 0.f, 0.f, 0.f};
  if (s >= n - 1) {
    const int* row = ids + b * S_;
    unsigned long long mix = 0ull;
    for (int p = 0; p < n; ++p)
      mix ^= (unsigned long long)(unsigned int)row[s - n + 1 + p] * hp.mult[g][p];
    unsigned long long id = (mix + hp.off[g]) % 1023ull + 1ull;
    const float* e = emb + ((size_t)g * 1024 + id) * 96 + d0;
    float4 a = *reinterpret_cast<const float4*>(e);
    float4 c = *reinterpret_cast<const float4*>(e + 4);
    f[0] = a.x; f[1] = a.y; f[2] = a.z; f[3] = a.w;
    f[4] = c.x; f[5] = c.y; f[6] = c.z; f[7] = c.w;
  }
  store8b(mem + (size_t)token * 768 + (size_t)j * 8, f);
}

// ---------------- kernel 2: kv = memory @ [Wk;Wv]^T  (MFMA GEMM) -----------
// UNCHANGED (control for counter attribution).
__global__ __launch_bounds__(256) void k_gemm(
    const u16* __restrict__ A, const u16* __restrict__ Wk,
    const u16* __restrict__ Wv, u16* __restrict__ KV) {
  __shared__ u16 As[128 * 32];
  __shared__ u16 Bs[128 * 32];

  int L = blockIdx.x;          // 0..3071
  int xcd = L & 7;
  int idx = L >> 3;            // 0..383
  int mtl = idx / 12;          // 0..31
  int nt = idx - mtl * 12;     // 0..11
  int mt = xcd * 32 + mtl;     // 0..255
  const int m0 = mt * 128;
  const u16* Wbase = (nt < 6) ? (Wk + (size_t)nt * 128 * 768)
                              : (Wv + (size_t)(nt - 6) * 128 * 768);
  const int colbase = nt * 128;

  const int tid = threadIdx.x;
  const int lane = tid & 63;
  const int wv = tid >> 6;
  const int wr = (wv >> 1) * 64;
  const int wc = (wv & 1) * 64;
  const int m16 = lane & 15;
  const int g8 = (lane >> 4) * 8;

  f32x4 acc[4][4];
#pragma unroll
  for (int i = 0; i < 4; ++i)
#pragma unroll
    for (int j = 0; j < 4; ++j) acc[i][j] = (f32x4){0.f, 0.f, 0.f, 0.f};

  for (int kt = 0; kt < 24; ++kt) {
    const int k0 = kt * 32;
#pragma unroll
    for (int i = 0; i < 2; ++i) {
      int c = tid + i * 256;
      int row = c >> 2;
      int kk = (c & 3) * 8;
      gl_lds16(A + (size_t)(m0 + row) * 768 + k0 + kk, &As[c * 8]);
      gl_lds16(Wbase + (size_t)row * 768 + k0 + kk, &Bs[c * 8]);
    }
    __syncthreads();
    bf16x8 af[4], bfr[4];
#pragma unroll
    for (int mi = 0; mi < 4; ++mi)
      af[mi] = *reinterpret_cast<const bf16x8*>(&As[(wr + mi * 16 + m16) * 32 + g8]);
#pragma unroll
    for (int ni = 0; ni < 4; ++ni)
      bfr[ni] = *reinterpret_cast<const bf16x8*>(&Bs[(wc + ni * 16 + m16) * 32 + g8]);
#pragma unroll
    for (int mi = 0; mi < 4; ++mi)
#pragma unroll
      for (int ni = 0; ni < 4; ++ni)
        acc[mi][ni] = __builtin_amdgcn_mfma_f32_16x16x32_bf16(af[mi], bfr[ni],
                                                              acc[mi][ni], 0, 0, 0);
    __syncthreads();
  }

  const int r0 = (lane >> 4) * 4;
#pragma unroll
  for (int mi = 0; mi < 4; ++mi) {
#pragma unroll
    for (int r = 0; r < 4; ++r) {
      int row = m0 + wr + mi * 16 + r0 + r;
      size_t base = (size_t)row * 1536 + colbase + wc;
#pragma unroll
      for (int ni = 0; ni < 4; ++ni)
        KV[base + ni * 16 + m16] = f2b(acc[mi][ni][r]);
    }
  }
}

// ---------------- kernel 3: fused RMSNorm+gate+conv ------------------------
// Round-10 change: kill scalar-gather weight loads.
//  - Phase 1: knw/vnw hoisted to 24 regs (c0 fixed per lane across jobs).
//  - Phase 2: fixed channel-chunk per thread (192 thr: cg=tid%96,
//    r=(tid/96)*16+it, 16 iters) so cw hoists to 24 regs loaded once.
#define T_TOK 32
#define LROW 776   // 768 + 8 pad (u16)
__global__ __launch_bounds__(256) void k_epiconv(
    const u16* __restrict__ KV, const float* __restrict__ hid,
    const float* __restrict__ knw, const float* __restrict__ vnw,
    const float* __restrict__ cw, float* __restrict__ out) {
  __shared__ u16 gl[(T_TOK + 2) * LROW];  // 52,768 B

  const int t0 = blockIdx.x * T_TOK;
  const int s0 = t0 & (S_ - 1);
  const int w = threadIdx.x >> 6;
  const int lane = threadIdx.x & 63;
  const int c0 = lane * 12;

  // hoist norm weights: fixed per lane across all phase-1 jobs
  float nk[12], nv[12];
#pragma unroll
  for (int q = 0; q < 3; ++q) {
    float4 a = *reinterpret_cast<const float4*>(knw + c0 + q * 4);
    float4 b = *reinterpret_cast<const float4*>(vnw + c0 + q * 4);
    nk[q * 4 + 0] = a.x; nk[q * 4 + 1] = a.y;
    nk[q * 4 + 2] = a.z; nk[q * 4 + 3] = a.w;
    nv[q * 4 + 0] = b.x; nv[q * 4 + 1] = b.y;
    nv[q * 4 + 2] = b.z; nv[q * 4 + 3] = b.w;
  }

  // ---- phase 1: epi for jobs j=0..33 (token t0+j-2), wave-strided ----
  for (int j = w; j < T_TOK + 2; j += 4) {
    if (!(s0 == 0 && j < 2)) {  // skip nonexistent tokens before sequence start
      const int token = t0 + j - 2;
      const u16* kr = KV + (size_t)token * 1536 + c0;
      const u16* vr = kr + 768;
      const float* hr = hid + (size_t)token * 768 + c0;

      float k[12], v[12], h[12];
#pragma unroll
      for (int q = 0; q < 3; ++q) {
        ushort4 a = *reinterpret_cast<const ushort4*>(kr + q * 4);
        ushort4 b = *reinterpret_cast<const ushort4*>(vr + q * 4);
        float4 c = *reinterpret_cast<const float4*>(hr + q * 4);
        k[q * 4 + 0] = b2f(a.x); k[q * 4 + 1] = b2f(a.y);
        k[q * 4 + 2] = b2f(a.z); k[q * 4 + 3] = b2f(a.w);
        v[q * 4 + 0] = b2f(b.x); v[q * 4 + 1] = b2f(b.y);
        v[q * 4 + 2] = b2f(b.z); v[q * 4 + 3] = b2f(b.w);
        h[q * 4 + 0] = c.x; h[q * 4 + 1] = c.y;
        h[q * 4 + 2] = c.z; h[q * 4 + 3] = c.w;
      }
      float ssk = 0.f, ssv = 0.f;
#pragma unroll
      for (int i = 0; i < 12; ++i) { ssk += k[i] * k[i]; ssv += v[i] * v[i]; }
#pragma unroll
      for (int off = 1; off < 64; off <<= 1) {
        ssk += __shfl_xor(ssk, off);
        ssv += __shfl_xor(ssv, off);
      }
      float rk = rsqrtf(ssk * (1.f / 768.f) + 1e-6f);
      float rv = rsqrtf(ssv * (1.f / 768.f) + 1e-6f);

      float dot = 0.f;
#pragma unroll
      for (int i = 0; i < 12; ++i) dot += h[i] * (k[i] * rk * nk[i]);
#pragma unroll
      for (int off = 1; off < 64; off <<= 1) dot += __shfl_xor(dot, off);
      float gate = 1.f / (1.f + expf(-dot * 0.03608439182435161f));  // 1/sqrt(768)

      u16* go = &gl[j * LROW + c0];
#pragma unroll
      for (int q = 0; q < 3; ++q) {
        ushort4 u;
        u.x = f2b(gate * v[q * 4 + 0] * rv * nv[q * 4 + 0]);
        u.y = f2b(gate * v[q * 4 + 1] * rv * nv[q * 4 + 1]);
        u.z = f2b(gate * v[q * 4 + 2] * rv * nv[q * 4 + 2]);
        u.w = f2b(gate * v[q * 4 + 3] * rv * nv[q * 4 + 3]);
        *reinterpret_cast<ushort4*>(go + q * 4) = u;
      }
    }
  }
  __syncthreads();

  // ---- phase 2: conv; 192 threads x 16 rows, fixed channel chunk ----
  if (threadIdx.x < 192) {
    const int cg = threadIdx.x % 96;
    const int rbase = (threadIdx.x / 96) * 16;
    const int cc0 = cg * 8;

    // hoist conv weights: 24 consecutive floats (96B-aligned), once
    float cwf[24];
#pragma unroll
    for (int q = 0; q < 6; ++q) {
      float4 t = *reinterpret_cast<const float4*>(cw + cc0 * 3 + q * 4);
      cwf[q * 4 + 0] = t.x; cwf[q * 4 + 1] = t.y;
      cwf[q * 4 + 2] = t.z; cwf[q * 4 + 3] = t.w;
    }

    for (int it = 0; it < 16; ++it) {
      int r = rbase + it;
      int s = s0 + r;

      float acc[8] = {0.f, 0.f, 0.f, 0.f, 0.f, 0.f, 0.f, 0.f};
      if (s >= 2) {
        F8 x0 = load8b(&gl[r * LROW + cc0]);          // d=-2 (kk=0)
#pragma unroll
        for (int i = 0; i < 8; ++i) acc[i] += x0.f[i] * cwf[i * 3 + 0];
      }
      if (s >= 1) {
        F8 x1 = load8b(&gl[(r + 1) * LROW + cc0]);    // d=-1 (kk=1)
#pragma unroll
        for (int i = 0; i < 8; ++i) acc[i] += x1.f[i] * cwf[i * 3 + 1];
      }
      {
        F8 x2 = load8b(&gl[(r + 2) * LROW + cc0]);    // d=0  (kk=2)
#pragma unroll
        for (int i = 0; i < 8; ++i) acc[i] += x2.f[i] * cwf[i * 3 + 2];
      }
      float* op = out + (size_t)(t0 + r) * 768 + cc0;
      *reinterpret_cast<float4*>(op) = make_float4(acc[0], acc[1], acc[2], acc[3]);
      *reinterpret_cast<float4*>(op + 4) = make_float4(acc[4], acc[5], acc[6], acc[7]);
    }
  }
}

// ---------------- launch ---------------------------------------------------
extern "C" void kernel_launch(void* const* d_in, const int* in_sizes, int n_in,
                              void* d_out, int out_size, void* d_ws, size_t ws_size,
                              hipStream_t stream) {
  const float* hid = (const float*)d_in[0];
  const int* ids = (const int*)d_in[1];
  const float* emb = (const float*)d_in[2];
  const float* wk  = (const float*)d_in[3];
  const float* wvw = (const float*)d_in[4];
  const float* knw = (const float*)d_in[5];
  const float* vnw = (const float*)d_in[6];
  const float* cw  = (const float*)d_in[7];
  float* out = (float*)d_out;

  char* ws = (char*)d_ws;
  u16* mem = (u16*)ws;                        // 32768*768*2  = 50,331,648 B
  u16* kv  = (u16*)(ws + 50331648);           // 32768*1536*2 = 100,663,296 B
  u16* wkb = (u16*)(ws + 150994944);          // 768*768*2 = 1,179,648 B
  u16* wvb = (u16*)(ws + 152174592);          // 768*768*2

  HashP hp = make_hashp();

  k_w2b<<<576, 256, 0, stream>>>(wk, wvw, wkb, wvb);
  k_hash_gather<<<12288, 256, 0, stream>>>(ids, emb, mem, hp);
  k_gemm<<<3072, 256, 0, stream>>>(mem, wkb, wvb, kv);
  k_epiconv<<<1024, 256, 0, stream>>>(kv, hid, knw, vnw, cw, out);
}

// Round 15
// 320.253 us; speedup vs baseline: 1.1957x; 1.0348x over previous
//
#include <hip/hip_runtime.h>
#include <hip/hip_bf16.h>
#include <stdint.h>

#define B_ 4
#define S_ 8192
#define HID 768
#define NTOK (B_ * S_)  // 32768

typedef unsigned short u16;
typedef __bf16 bf16x8 __attribute__((ext_vector_type(8)));
typedef float f32x4 __attribute__((ext_vector_type(4)));

// ---------------- hash parameters (host-computed, passed by value) ----------
struct HashP {
  unsigned long long mult[8][3];
  unsigned long long off[8];
};

static HashP make_hashp() {
  HashP hp;
  const long long max_int = 2147483647LL;  // 2^31 - 1
  int gi = 0;
  const int ngrams[2] = {2, 3};
  for (int t = 0; t < 2; ++t) {
    int n = ngrams[t];
    for (int h = 0; h < 4; ++h) {
      long long base = 17 + 10007 * 1 + 1543 * (n + 1) + 8191 * (h + 1);
      for (int p = 0; p < 3; ++p) hp.mult[gi][p] = 0ull;
      for (int p = 0; p < n; ++p) {
        long long v = (base + 32771LL * (p + 1) + 65537LL * (h + 1) * (p + 1)) % max_int;
        hp.mult[gi][p] = (unsigned long long)(v * 2 + 1);
      }
      hp.off[gi] = (unsigned long long)(((base * max_int) + 97LL * (n + h + 1)) % max_int);
      ++gi;
    }
  }
  return hp;
}

// ---------------- small helpers -------------------------------------------
__device__ __forceinline__ float b2f(u16 u) {
  union { unsigned int i; float f; } c;
  c.i = ((unsigned int)u) << 16;
  return c.f;
}
__device__ __forceinline__ u16 f2b(float f) {  // RNE
  union { float f; unsigned int i; } c;
  c.f = f;
  unsigned int r = c.i + 0x7fffu + ((c.i >> 16) & 1u);
  return (u16)(r >> 16);
}

// store 8 floats as 8 bf16 (16B)
__device__ __forceinline__ void store8b(u16* p, const float* f) {
  uint4 u;
  u.x = (unsigned)f2b(f[0]) | ((unsigned)f2b(f[1]) << 16);
  u.y = (unsigned)f2b(f[2]) | ((unsigned)f2b(f[3]) << 16);
  u.z = (unsigned)f2b(f[4]) | ((unsigned)f2b(f[5]) << 16);
  u.w = (unsigned)f2b(f[6]) | ((unsigned)f2b(f[7]) << 16);
  *reinterpret_cast<uint4*>(p) = u;
}
// load 8 bf16 -> 8 floats (works for global or LDS pointers)
struct F8 { float f[8]; };
__device__ __forceinline__ F8 load8b(const u16* p) {  // 16B-aligned
  uint4 u = *reinterpret_cast<const uint4*>(p);
  F8 r;
  r.f[0] = b2f((u16)(u.x & 0xffffu)); r.f[1] = b2f((u16)(u.x >> 16));
  r.f[2] = b2f((u16)(u.y & 0xffffu)); r.f[3] = b2f((u16)(u.y >> 16));
  r.f[4] = b2f((u16)(u.z & 0xffffu)); r.f[5] = b2f((u16)(u.z >> 16));
  r.f[6] = b2f((u16)(u.w & 0xffffu)); r.f[7] = b2f((u16)(u.w >> 16));
  return r;
}

// global -> LDS direct copy, 16 B per lane (CK addrspace-cast idiom)
__device__ __forceinline__ void gl_lds16(const void* g, void* l) {
  auto gp = reinterpret_cast<const __attribute__((address_space(1))) void*>(
      reinterpret_cast<uintptr_t>(g));
  auto lp = reinterpret_cast<__attribute__((address_space(3))) void*>(
      reinterpret_cast<uintptr_t>(l));
  __builtin_amdgcn_global_load_lds(gp, lp, 16, 0, 0);
}

// ---------------- kernel 0: convert Wk,Wv fp32 -> bf16 ---------------------
__global__ __launch_bounds__(256) void k_w2b(
    const float* __restrict__ wk, const float* __restrict__ wv,
    u16* __restrict__ wkb, u16* __restrict__ wvb) {
  int t = blockIdx.x * 256 + threadIdx.x;     // 0..147455, 8 elems each
  const float* src;
  u16* dst;
  int off;
  if (t < 73728) { src = wk; dst = wkb; off = t * 8; }
  else           { src = wv; dst = wvb; off = (t - 73728) * 8; }
  float4 a = *reinterpret_cast<const float4*>(src + off);
  float4 b = *reinterpret_cast<const float4*>(src + off + 4);
  float f[8] = {a.x, a.y, a.z, a.w, b.x, b.y, b.z, b.w};
  store8b(dst + off, f);
}

// ---------------- kernel 1: hash + embedding gather -> memory (bf16) -------
// UNCHANGED (control).
__global__ __launch_bounds__(256) void k_hash_gather(
    const int* __restrict__ ids, const float* __restrict__ emb,
    u16* __restrict__ mem, HashP hp) {
  int tid = blockIdx.x * 256 + threadIdx.x;
  int token = tid / 96;
  int j = tid - token * 96;  // 0..95 : head g = j/12, d0 = (j%12)*8
  if (token >= NTOK) return;
  int b = token >> 13;
  int s = token & (S_ - 1);
  int g = j / 12;
  int d0 = (j - g * 12) * 8;
  int n = (g < 4) ? 2 : 3;
  float f[8] = {0.f, 0.f, 0.f, 0.f, 0.f, 0.f, 0.f, 0.f};
  if (s >= n - 1) {
    const int* row = ids + b * S_;
    unsigned long long mix = 0ull;
    for (int p = 0; p < n; ++p)
      mix ^= (unsigned long long)(unsigned int)row[s - n + 1 + p] * hp.mult[g][p];
    unsigned long long id = (mix + hp.off[g]) % 1023ull + 1ull;
    const float* e = emb + ((size_t)g * 1024 + id) * 96 + d0;
    float4 a = *reinterpret_cast<const float4*>(e);
    float4 c = *reinterpret_cast<const float4*>(e + 4);
    f[0] = a.x; f[1] = a.y; f[2] = a.z; f[3] = a.w;
    f[4] = c.x; f[5] = c.y; f[6] = c.z; f[7] = c.w;
  }
  store8b(mem + (size_t)token * 768 + (size_t)j * 8, f);
}

// ---------------- kernel 2: kv = memory @ [Wk;Wv]^T  (MFMA GEMM) -----------
// Round-14 change: BK 32 -> 64 (K-steps 24 -> 12, barrier drains halved;
// m233 model: 2-phase overhead is per-K-step). 128B LDS rows would be a
// 16-way bank conflict, so granule XOR-swizzle kg ^= (row&7), applied as
// pre-swizzled GLOBAL source (linear global_load_lds dest) + swizzled
// ds_read address (rule #21: same involution both sides).
__global__ __launch_bounds__(256) void k_gemm(
    const u16* __restrict__ A, const u16* __restrict__ Wk,
    const u16* __restrict__ Wv, u16* __restrict__ KV) {
  __shared__ u16 As[128 * 64];   // 16 KB
  __shared__ u16 Bs[128 * 64];   // 16 KB

  int L = blockIdx.x;          // 0..3071
  int xcd = L & 7;
  int idx = L >> 3;            // 0..383
  int mtl = idx / 12;          // 0..31
  int nt = idx - mtl * 12;     // 0..11
  int mt = xcd * 32 + mtl;     // 0..255
  const int m0 = mt * 128;
  const u16* Wbase = (nt < 6) ? (Wk + (size_t)nt * 128 * 768)
                              : (Wv + (size_t)(nt - 6) * 128 * 768);
  const int colbase = nt * 128;

  const int tid = threadIdx.x;
  const int lane = tid & 63;
  const int wv = tid >> 6;
  const int wr = (wv >> 1) * 64;
  const int wc = (wv & 1) * 64;
  const int m16 = lane & 15;
  const int g4 = lane >> 4;        // logical k-granule within kstep (0..3)

  f32x4 acc[4][4];
#pragma unroll
  for (int i = 0; i < 4; ++i)
#pragma unroll
    for (int j = 0; j < 4; ++j) acc[i][j] = (f32x4){0.f, 0.f, 0.f, 0.f};

  for (int kt = 0; kt < 12; ++kt) {
    const int k0 = kt * 64;
    // stage one K-tile: 1024 granules per matrix; 4 iters x 256 thr
#pragma unroll
    for (int i = 0; i < 4; ++i) {
      int c = tid + i * 256;             // LDS granule (linear dest)
      int row = c >> 3;                  // 8 granules per 64-elem row
      int kgl = ((c & 7) ^ (row & 7)) * 8;  // pre-swizzled source k-offset
      gl_lds16(A + (size_t)(m0 + row) * 768 + k0 + kgl, &As[c * 8]);
      gl_lds16(Wbase + (size_t)row * 768 + k0 + kgl, &Bs[c * 8]);
    }
    __syncthreads();
#pragma unroll
    for (int ks = 0; ks < 2; ++ks) {
      const int kgL = ks * 4 + g4;       // logical k-granule in [0,8)
      bf16x8 af[4], bfr[4];
#pragma unroll
      for (int mi = 0; mi < 4; ++mi) {
        int row = wr + mi * 16 + m16;
        af[mi] = *reinterpret_cast<const bf16x8*>(
            &As[row * 64 + ((kgL ^ (row & 7)) << 3)]);
      }
#pragma unroll
      for (int ni = 0; ni < 4; ++ni) {
        int row = wc + ni * 16 + m16;
        bfr[ni] = *reinterpret_cast<const bf16x8*>(
            &Bs[row * 64 + ((kgL ^ (row & 7)) << 3)]);
      }
#pragma unroll
      for (int mi = 0; mi < 4; ++mi)
#pragma unroll
        for (int ni = 0; ni < 4; ++ni)
          acc[mi][ni] = __builtin_amdgcn_mfma_f32_16x16x32_bf16(af[mi], bfr[ni],
                                                                acc[mi][ni], 0, 0, 0);
    }
    __syncthreads();
  }

  const int r0 = (lane >> 4) * 4;
#pragma unroll
  for (int mi = 0; mi < 4; ++mi) {
#pragma unroll
    for (int r = 0; r < 4; ++r) {
      int row = m0 + wr + mi * 16 + r0 + r;
      size_t base = (size_t)row * 1536 + colbase + wc;
#pragma unroll
      for (int ni = 0; ni < 4; ++ni)
        KV[base + ni * 16 + m16] = f2b(acc[mi][ni][r]);
    }
  }
}

// ---------------- kernel 3: fused RMSNorm+gate+conv ------------------------
// UNCHANGED (control).
#define T_TOK 32
#define LROW 776   // 768 + 8 pad (u16)
__global__ __launch_bounds__(256) void k_epiconv(
    const u16* __restrict__ KV, const float* __restrict__ hid,
    const float* __restrict__ knw, const float* __restrict__ vnw,
    const float* __restrict__ cw, float* __restrict__ out) {
  __shared__ u16 gl[(T_TOK + 2) * LROW];  // 52,768 B

  const int t0 = blockIdx.x * T_TOK;
  const int s0 = t0 & (S_ - 1);
  const int w = threadIdx.x >> 6;
  const int lane = threadIdx.x & 63;
  const int c0 = lane * 12;

  // hoist norm weights: fixed per lane across all phase-1 jobs
  float nk[12], nv[12];
#pragma unroll
  for (int q = 0; q < 3; ++q) {
    float4 a = *reinterpret_cast<const float4*>(knw + c0 + q * 4);
    float4 b = *reinterpret_cast<const float4*>(vnw + c0 + q * 4);
    nk[q * 4 + 0] = a.x; nk[q * 4 + 1] = a.y;
    nk[q * 4 + 2] = a.z; nk[q * 4 + 3] = a.w;
    nv[q * 4 + 0] = b.x; nv[q * 4 + 1] = b.y;
    nv[q * 4 + 2] = b.z; nv[q * 4 + 3] = b.w;
  }

  // ---- phase 1: epi for jobs j=0..33 (token t0+j-2), wave-strided ----
  for (int j = w; j < T_TOK + 2; j += 4) {
    if (!(s0 == 0 && j < 2)) {  // skip nonexistent tokens before sequence start
      const int token = t0 + j - 2;
      const u16* kr = KV + (size_t)token * 1536 + c0;
      const u16* vr = kr + 768;
      const float* hr = hid + (size_t)token * 768 + c0;

      float k[12], v[12], h[12];
#pragma unroll
      for (int q = 0; q < 3; ++q) {
        ushort4 a = *reinterpret_cast<const ushort4*>(kr + q * 4);
        ushort4 b = *reinterpret_cast<const ushort4*>(vr + q * 4);
        float4 c = *reinterpret_cast<const float4*>(hr + q * 4);
        k[q * 4 + 0] = b2f(a.x); k[q * 4 + 1] = b2f(a.y);
        k[q * 4 + 2] = b2f(a.z); k[q * 4 + 3] = b2f(a.w);
        v[q * 4 + 0] = b2f(b.x); v[q * 4 + 1] = b2f(b.y);
        v[q * 4 + 2] = b2f(b.z); v[q * 4 + 3] = b2f(b.w);
        h[q * 4 + 0] = c.x; h[q * 4 + 1] = c.y;
        h[q * 4 + 2] = c.z; h[q * 4 + 3] = c.w;
      }
      float ssk = 0.f, ssv = 0.f;
#pragma unroll
      for (int i = 0; i < 12; ++i) { ssk += k[i] * k[i]; ssv += v[i] * v[i]; }
#pragma unroll
      for (int off = 1; off < 64; off <<= 1) {
        ssk += __shfl_xor(ssk, off);
        ssv += __shfl_xor(ssv, off);
      }
      float rk = rsqrtf(ssk * (1.f / 768.f) + 1e-6f);
      float rv = rsqrtf(ssv * (1.f / 768.f) + 1e-6f);

      float dot = 0.f;
#pragma unroll
      for (int i = 0; i < 12; ++i) dot += h[i] * (k[i] * rk * nk[i]);
#pragma unroll
      for (int off = 1; off < 64; off <<= 1) dot += __shfl_xor(dot, off);
      float gate = 1.f / (1.f + expf(-dot * 0.03608439182435161f));  // 1/sqrt(768)

      u16* go = &gl[j * LROW + c0];
#pragma unroll
      for (int q = 0; q < 3; ++q) {
        ushort4 u;
        u.x = f2b(gate * v[q * 4 + 0] * rv * nv[q * 4 + 0]);
        u.y = f2b(gate * v[q * 4 + 1] * rv * nv[q * 4 + 1]);
        u.z = f2b(gate * v[q * 4 + 2] * rv * nv[q * 4 + 2]);
        u.w = f2b(gate * v[q * 4 + 3] * rv * nv[q * 4 + 3]);
        *reinterpret_cast<ushort4*>(go + q * 4) = u;
      }
    }
  }
  __syncthreads();

  // ---- phase 2: conv; 192 threads x 16 rows, fixed channel chunk ----
  if (threadIdx.x < 192) {
    const int cg = threadIdx.x % 96;
    const int rbase = (threadIdx.x / 96) * 16;
    const int cc0 = cg * 8;

    // hoist conv weights: 24 consecutive floats (96B-aligned), once
    float cwf[24];
#pragma unroll
    for (int q = 0; q < 6; ++q) {
      float4 t = *reinterpret_cast<const float4*>(cw + cc0 * 3 + q * 4);
      cwf[q * 4 + 0] = t.x; cwf[q * 4 + 1] = t.y;
      cwf[q * 4 + 2] = t.z; cwf[q * 4 + 3] = t.w;
    }

    for (int it = 0; it < 16; ++it) {
      int r = rbase + it;
      int s = s0 + r;

      float acc[8] = {0.f, 0.f, 0.f, 0.f, 0.f, 0.f, 0.f, 0.f};
      if (s >= 2) {
        F8 x0 = load8b(&gl[r * LROW + cc0]);          // d=-2 (kk=0)
#pragma unroll
        for (int i = 0; i < 8; ++i) acc[i] += x0.f[i] * cwf[i * 3 + 0];
      }
      if (s >= 1) {
        F8 x1 = load8b(&gl[(r + 1) * LROW + cc0]);    // d=-1 (kk=1)
#pragma unroll
        for (int i = 0; i < 8; ++i) acc[i] += x1.f[i] * cwf[i * 3 + 1];
      }
      {
        F8 x2 = load8b(&gl[(r + 2) * LROW + cc0]);    // d=0  (kk=2)
#pragma unroll
        for (int i = 0; i < 8; ++i) acc[i] += x2.f[i] * cwf[i * 3 + 2];
      }
      float* op = out + (size_t)(t0 + r) * 768 + cc0;
      *reinterpret_cast<float4*>(op) = make_float4(acc[0], acc[1], acc[2], acc[3]);
      *reinterpret_cast<float4*>(op + 4) = make_float4(acc[4], acc[5], acc[6], acc[7]);
    }
  }
}

// ---------------- launch ---------------------------------------------------
extern "C" void kernel_launch(void* const* d_in, const int* in_sizes, int n_in,
                              void* d_out, int out_size, void* d_ws, size_t ws_size,
                              hipStream_t stream) {
  const float* hid = (const float*)d_in[0];
  const int* ids = (const int*)d_in[1];
  const float* emb = (const float*)d_in[2];
  const float* wk  = (const float*)d_in[3];
  const float* wvw = (const float*)d_in[4];
  const float* knw = (const float*)d_in[5];
  const float* vnw = (const float*)d_in[6];
  const float* cw  = (const float*)d_in[7];
  float* out = (float*)d_out;

  char* ws = (char*)d_ws;
  u16* mem = (u16*)ws;                        // 32768*768*2  = 50,331,648 B
  u16* kv  = (u16*)(ws + 50331648);           // 32768*1536*2 = 100,663,296 B
  u16* wkb = (u16*)(ws + 150994944);          // 768*768*2 = 1,179,648 B
  u16* wvb = (u16*)(ws + 152174592);          // 768*768*2

  HashP hp = make_hashp();

  k_w2b<<<576, 256, 0, stream>>>(wk, wvw, wkb, wvb);
  k_hash_gather<<<12288, 256, 0, stream>>>(ids, emb, mem, hp);
  k_gemm<<<3072, 256, 0, stream>>>(mem, wkb, wvb, kv);
  k_epiconv<<<1024, 256, 0, stream>>>(kv, hid, knw, vnw, cw, out);
}